// Round 1
// baseline (544.666 us; speedup 1.0000x reference)
//
#include <hip/hip_runtime.h>
#include <hip/hip_bf16.h>

#define B 64
#define T 2000
#define D_MEM 512
#define D_Q 1024
#define D_ATT 128
#define C_LOC 32
#define K 31

// ws layout (floats)
#define WS_PQ       0                        // B*D_ATT = 8192
#define WS_ENERGY   (WS_PQ + B*D_ATT)        // B*T = 128000
#define NCHUNK      10
#define TCHUNK      (T / NCHUNK)             // 200
#define WS_PARTIAL  (WS_ENERGY + B*T)        // NCHUNK*B*D_MEM = 327680

__device__ __forceinline__ float tanh_fast(float x) {
    float e = __expf(2.f * x);
    return 1.f - 2.f / (e + 1.f);
}

// K1: processed_query[b,d] = sum_i h[b,i] * Wq[i,d].  grid(B), block(128)
__global__ void pq_kernel(const float* __restrict__ h, const float* __restrict__ Wq,
                          float* __restrict__ pq) {
    int b = blockIdx.x;
    int d = threadIdx.x;                       // 0..127
    __shared__ float sh[D_Q];
    const float* hb = h + (size_t)b * D_Q;
    for (int i = threadIdx.x; i < D_Q / 4; i += 128)
        ((float4*)sh)[i] = ((const float4*)hb)[i];
    __syncthreads();
    float acc = 0.f;
#pragma unroll 8
    for (int i = 0; i < D_Q; ++i)
        acc = fmaf(sh[i], Wq[(size_t)i * D_ATT + d], acc);
    pq[b * D_ATT + d] = acc;
}

// K2: energies[b,t] = v . tanh(pq + Wloc^T.conv(aw) + pmem)
// grid(T/16, B), block(256). Each block: 16 t values.
#define CH 16
__global__ void energy_kernel(const float* __restrict__ aw,
                              const float* __restrict__ pmem,
                              const float* __restrict__ pq,
                              const float* __restrict__ Wconv,
                              const float* __restrict__ bconv,
                              const float* __restrict__ Wloc,
                              const float* __restrict__ v,
                              float* __restrict__ energies) {
    const int b  = blockIdx.y;
    const int t0 = blockIdx.x * CH;
    const int tid = threadIdx.x;

    __shared__ float s_aw[2][CH + K - 1];          // [2][46]
    __shared__ float s_wc[2 * K * C_LOC];          // transposed: [(i*31+k)*32 + c]
    __shared__ float s_loc[CH][C_LOC];
    __shared__ float s_pq[D_ATT];

    // stage aw slice: t in [t0-15, t0+CH+15)
    for (int j = tid; j < 2 * (CH + K - 1); j += 256) {
        int i = j / (CH + K - 1), o = j % (CH + K - 1);
        int t = t0 - (K / 2) + o;
        s_aw[i][o] = (t >= 0 && t < T) ? aw[((size_t)b * 2 + i) * T + t] : 0.f;
    }
    // stage Wconv transposed (coalesced global read)
    for (int j = tid; j < C_LOC * 2 * K; j += 256) {
        int c = j / (2 * K), r = j % (2 * K);
        int i = r / K, k = r % K;
        s_wc[(i * K + k) * C_LOC + c] = Wconv[j];
    }
    if (tid < D_ATT) s_pq[tid] = pq[b * D_ATT + tid];
    __syncthreads();

    // conv: thread (tt=tid>>5 in 0..7, c=tid&31) computes loc for t0+tt and t0+tt+8
    {
        int tt = tid >> 5, c = tid & 31;
        float bc = bconv[c];
        float acc0 = bc, acc1 = bc;
#pragma unroll
        for (int i = 0; i < 2; ++i) {
#pragma unroll
            for (int k = 0; k < K; ++k) {
                float wv = s_wc[(i * K + k) * C_LOC + c];
                acc0 = fmaf(s_aw[i][tt + k],     wv, acc0);
                acc1 = fmaf(s_aw[i][tt + 8 + k], wv, acc1);
            }
        }
        s_loc[tt][c] = acc0;
        s_loc[tt + 8][c] = acc1;
    }
    __syncthreads();

    // energy: thread (tt=tid>>5, dd=tid&31) handles d = dd*4..dd*4+3 for t0+iter*8+tt
    int tt = tid >> 5, dd = tid & 31;
    float4 pqv = ((const float4*)s_pq)[dd];
    float4 vv  = ((const float4*)v)[dd];
#pragma unroll
    for (int iter = 0; iter < 2; ++iter) {
        int ts = iter * 8 + tt;
        int t = t0 + ts;
        float4 pm = ((const float4*)(pmem + ((size_t)b * T + t) * D_ATT))[dd];
        float4 pl = {0.f, 0.f, 0.f, 0.f};
#pragma unroll
        for (int c = 0; c < C_LOC; ++c) {
            float l = s_loc[ts][c];
            float4 w = ((const float4*)(Wloc + c * D_ATT))[dd];
            pl.x = fmaf(l, w.x, pl.x);
            pl.y = fmaf(l, w.y, pl.y);
            pl.z = fmaf(l, w.z, pl.z);
            pl.w = fmaf(l, w.w, pl.w);
        }
        float e = vv.x * tanh_fast(pqv.x + pl.x + pm.x)
                + vv.y * tanh_fast(pqv.y + pl.y + pm.y)
                + vv.z * tanh_fast(pqv.z + pl.z + pm.z)
                + vv.w * tanh_fast(pqv.w + pl.w + pm.w);
        // reduce across the 32 dd-lanes (xor masks <=16 stay within the 32-group)
#pragma unroll
        for (int off = 16; off >= 1; off >>= 1)
            e += __shfl_xor(e, off);
        if (dd == 0) energies[(size_t)b * T + t] = e;
    }
}

// K3: softmax over T per batch; writes normalized weights to d_out.  grid(B), block(256)
__global__ void softmax_kernel(const float* __restrict__ energies,
                               float* __restrict__ weights) {
    int b = blockIdx.x, tid = threadIdx.x;
    const float* e = energies + (size_t)b * T;
    float vals[8];
    float m = -1e30f;
#pragma unroll
    for (int j = 0; j < 8; ++j) {
        int t = j * 256 + tid;
        vals[j] = (t < T) ? e[t] : -1e30f;
        m = fmaxf(m, vals[j]);
    }
    __shared__ float smax[4], ssum[4];
    int wid = tid >> 6, lane = tid & 63;
#pragma unroll
    for (int off = 32; off >= 1; off >>= 1) m = fmaxf(m, __shfl_xor(m, off));
    if (lane == 0) smax[wid] = m;
    __syncthreads();
    m = fmaxf(fmaxf(smax[0], smax[1]), fmaxf(smax[2], smax[3]));

    float s = 0.f;
#pragma unroll
    for (int j = 0; j < 8; ++j) {
        int t = j * 256 + tid;
        vals[j] = (t < T) ? __expf(vals[j] - m) : 0.f;
        s += vals[j];
    }
#pragma unroll
    for (int off = 32; off >= 1; off >>= 1) s += __shfl_xor(s, off);
    if (lane == 0) ssum[wid] = s;
    __syncthreads();
    s = ssum[0] + ssum[1] + ssum[2] + ssum[3];
    float inv = 1.f / s;
#pragma unroll
    for (int j = 0; j < 8; ++j) {
        int t = j * 256 + tid;
        if (t < T) weights[(size_t)b * T + t] = vals[j] * inv;
    }
}

// K4: partial context. grid(NCHUNK, B), block(128). Each thread one d-quad.
__global__ void ctx_partial_kernel(const float* __restrict__ memory,
                                   const float* __restrict__ weights,
                                   float* __restrict__ partial) {
    int b = blockIdx.y, s = blockIdx.x;
    int dq = threadIdx.x;                       // 0..127
    int tbeg = s * TCHUNK;
    __shared__ float sw[TCHUNK];
    const float* w = weights + (size_t)b * T;
    for (int j = threadIdx.x; j < TCHUNK; j += 128) sw[j] = w[tbeg + j];
    __syncthreads();
    const float4* mem4 = (const float4*)(memory + (size_t)b * T * D_MEM);
    float4 acc = {0.f, 0.f, 0.f, 0.f};
#pragma unroll 8
    for (int j = 0; j < TCHUNK; ++j) {
        float wt = sw[j];
        float4 mv = mem4[(size_t)(tbeg + j) * (D_MEM / 4) + dq];
        acc.x = fmaf(wt, mv.x, acc.x);
        acc.y = fmaf(wt, mv.y, acc.y);
        acc.z = fmaf(wt, mv.z, acc.z);
        acc.w = fmaf(wt, mv.w, acc.w);
    }
    ((float4*)(partial + ((size_t)s * B + b) * D_MEM))[dq] = acc;
}

// K5: reduce NCHUNK partials -> context in d_out.  grid(B*D_MEM/256), block(256)
__global__ void ctx_reduce_kernel(const float* __restrict__ partial,
                                  float* __restrict__ ctx) {
    int idx = blockIdx.x * 256 + threadIdx.x;   // 0 .. B*D_MEM-1
    float acc = 0.f;
#pragma unroll
    for (int s = 0; s < NCHUNK; ++s)
        acc += partial[(size_t)s * B * D_MEM + idx];
    ctx[idx] = acc;
}

extern "C" void kernel_launch(void* const* d_in, const int* in_sizes, int n_in,
                              void* d_out, int out_size, void* d_ws, size_t ws_size,
                              hipStream_t stream) {
    const float* hidden = (const float*)d_in[0];   // [B,1,D_Q]
    const float* memory = (const float*)d_in[1];   // [B,T,D_MEM]
    const float* pmem   = (const float*)d_in[2];   // [B,T,D_ATT]
    const float* aw     = (const float*)d_in[3];   // [B,2,T]
    const float* Wq     = (const float*)d_in[4];   // [D_Q,D_ATT]
    const float* Wconv  = (const float*)d_in[5];   // [C_LOC,2,K]
    const float* bconv  = (const float*)d_in[6];   // [C_LOC]
    const float* Wloc   = (const float*)d_in[7];   // [C_LOC,D_ATT]
    const float* v      = (const float*)d_in[8];   // [D_ATT]

    float* out_ctx = (float*)d_out;                // [B,D_MEM]
    float* out_w   = (float*)d_out + B * D_MEM;    // [B,T]

    float* ws       = (float*)d_ws;
    float* pq       = ws + WS_PQ;
    float* energies = ws + WS_ENERGY;
    float* partial  = ws + WS_PARTIAL;

    pq_kernel<<<B, 128, 0, stream>>>(hidden, Wq, pq);
    energy_kernel<<<dim3(T / CH, B), 256, 0, stream>>>(aw, pmem, pq, Wconv, bconv,
                                                       Wloc, v, energies);
    softmax_kernel<<<B, 256, 0, stream>>>(energies, out_w);
    ctx_partial_kernel<<<dim3(NCHUNK, B), 128, 0, stream>>>(memory, out_w, partial);
    ctx_reduce_kernel<<<(B * D_MEM) / 256, 256, 0, stream>>>(partial, out_ctx);
}

// Round 2
// 522.995 us; speedup vs baseline: 1.0414x; 1.0414x over previous
//
#include <hip/hip_runtime.h>
#include <hip/hip_bf16.h>

#define B 64
#define T 2000
#define D_MEM 512
#define D_Q 1024
#define D_ATT 128
#define C_LOC 32
#define K 31

// ws layout (floats)
#define WS_PQ       0                        // B*D_ATT = 8192
#define WS_ENERGY   (WS_PQ + B*D_ATT)        // B*T = 128000
#define NCHUNK      20
#define TCHUNK      (T / NCHUNK)             // 100
#define WS_PARTIAL  (WS_ENERGY + B*T)        // NCHUNK*B*D_MEM = 655360

__device__ __forceinline__ float tanh_fast(float x) {
    float e = __expf(2.f * x);
    return 1.f - 2.f / (e + 1.f);
}

// K1: pq[b,d] = sum_i h[b,i]*Wq[i,d]. grid(B), block(512): 4 i-slices x 128 d.
__global__ __launch_bounds__(512) void pq_kernel(const float* __restrict__ h,
                                                 const float* __restrict__ Wq,
                                                 float* __restrict__ pq) {
    int b = blockIdx.x;
    int tid = threadIdx.x;
    int ty = tid >> 7;          // 0..3  (i-slice)
    int d  = tid & 127;         // 0..127
    __shared__ float sh[D_Q];
    __shared__ float red[4][D_ATT];
    const float* hb = h + (size_t)b * D_Q;
    if (tid < D_Q / 4) ((float4*)sh)[tid] = ((const float4*)hb)[tid];
    __syncthreads();
    float acc = 0.f;
    int ibeg = ty * 256;
#pragma unroll 8
    for (int i2 = 0; i2 < 256; ++i2) {
        int i = ibeg + i2;
        acc = fmaf(sh[i], Wq[(size_t)i * D_ATT + d], acc);
    }
    red[ty][d] = acc;
    __syncthreads();
    if (ty == 0)
        pq[b * D_ATT + d] = red[0][d] + red[1][d] + red[2][d] + red[3][d];
}

// K2: energies[b,t] = v . tanh(pq + Wloc^T.conv(aw) + pmem)
// grid(T/CH, B), block(256). CH=40: each of 8 thread-groups owns 5 t's
// (t_local = g + 8*j), register-blocked so each Wloc float4 feeds 20 FMAs.
#define CH 40
#define TPT 5   // t's per thread-group
__global__ __launch_bounds__(256) void energy_kernel(const float* __restrict__ aw,
                              const float* __restrict__ pmem,
                              const float* __restrict__ pq,
                              const float* __restrict__ Wconv,
                              const float* __restrict__ bconv,
                              const float* __restrict__ Wloc,
                              const float* __restrict__ v,
                              float* __restrict__ energies) {
    const int b  = blockIdx.y;
    const int t0 = blockIdx.x * CH;
    const int tid = threadIdx.x;

    __shared__ float s_aw[2][CH + K - 1];          // [2][70]
    __shared__ float s_wc[2 * K * C_LOC];          // transposed: [(i*31+k)*32 + c]
    __shared__ float s_loc[CH][C_LOC];
    __shared__ float s_pq[D_ATT];

    // stage aw slice: t in [t0-15, t0+CH+15)
    for (int j = tid; j < 2 * (CH + K - 1); j += 256) {
        int i = j / (CH + K - 1), o = j % (CH + K - 1);
        int t = t0 - (K / 2) + o;
        s_aw[i][o] = (t >= 0 && t < T) ? aw[((size_t)b * 2 + i) * T + t] : 0.f;
    }
    // stage Wconv transposed (coalesced global read)
    for (int j = tid; j < C_LOC * 2 * K; j += 256) {
        int c = j / (2 * K), r = j % (2 * K);
        int i = r / K, k = r % K;
        s_wc[(i * K + k) * C_LOC + c] = Wconv[j];
    }
    if (tid < D_ATT) s_pq[tid] = pq[b * D_ATT + tid];
    __syncthreads();

    // conv: thread (g=tid>>5, c=tid&31) computes loc for t_local = g+8*j, j=0..4
    {
        int g = tid >> 5, c = tid & 31;
        float bc = bconv[c];
        float acc[TPT];
#pragma unroll
        for (int j = 0; j < TPT; ++j) acc[j] = bc;
#pragma unroll
        for (int i = 0; i < 2; ++i) {
#pragma unroll
            for (int k = 0; k < K; ++k) {
                float wv = s_wc[(i * K + k) * C_LOC + c];
#pragma unroll
                for (int j = 0; j < TPT; ++j)
                    acc[j] = fmaf(s_aw[i][g + 8 * j + k], wv, acc[j]);
            }
        }
#pragma unroll
        for (int j = 0; j < TPT; ++j) s_loc[g + 8 * j][c] = acc[j];
    }
    __syncthreads();

    // energy: thread (g=tid>>5, dd=tid&31) owns d-quad dd for t = t0+g+8*j.
    int g = tid >> 5, dd = tid & 31;
    float4 pqv = ((const float4*)s_pq)[dd];
    float4 vv  = ((const float4*)v)[dd];
    float4 pl[TPT];
#pragma unroll
    for (int j = 0; j < TPT; ++j) pl[j] = make_float4(0.f, 0.f, 0.f, 0.f);
#pragma unroll
    for (int c = 0; c < C_LOC; ++c) {
        float4 w = ((const float4*)(Wloc + c * D_ATT))[dd];
#pragma unroll
        for (int j = 0; j < TPT; ++j) {
            float l = s_loc[g + 8 * j][c];
            pl[j].x = fmaf(l, w.x, pl[j].x);
            pl[j].y = fmaf(l, w.y, pl[j].y);
            pl[j].z = fmaf(l, w.z, pl[j].z);
            pl[j].w = fmaf(l, w.w, pl[j].w);
        }
    }
#pragma unroll
    for (int j = 0; j < TPT; ++j) {
        int t = t0 + g + 8 * j;
        float4 pm = ((const float4*)(pmem + ((size_t)b * T + t) * D_ATT))[dd];
        float e = vv.x * tanh_fast(pqv.x + pl[j].x + pm.x)
                + vv.y * tanh_fast(pqv.y + pl[j].y + pm.y)
                + vv.z * tanh_fast(pqv.z + pl[j].z + pm.z)
                + vv.w * tanh_fast(pqv.w + pl[j].w + pm.w);
#pragma unroll
        for (int off = 16; off >= 1; off >>= 1)
            e += __shfl_xor(e, off);
        if (dd == 0) energies[(size_t)b * T + t] = e;
    }
}

// K3: softmax over T per batch; writes normalized weights to d_out. grid(B), block(256)
__global__ __launch_bounds__(256) void softmax_kernel(const float* __restrict__ energies,
                               float* __restrict__ weights) {
    int b = blockIdx.x, tid = threadIdx.x;
    const float* e = energies + (size_t)b * T;
    float vals[8];
    float m = -1e30f;
#pragma unroll
    for (int j = 0; j < 8; ++j) {
        int t = j * 256 + tid;
        vals[j] = (t < T) ? e[t] : -1e30f;
        m = fmaxf(m, vals[j]);
    }
    __shared__ float smax[4], ssum[4];
    int wid = tid >> 6, lane = tid & 63;
#pragma unroll
    for (int off = 32; off >= 1; off >>= 1) m = fmaxf(m, __shfl_xor(m, off));
    if (lane == 0) smax[wid] = m;
    __syncthreads();
    m = fmaxf(fmaxf(smax[0], smax[1]), fmaxf(smax[2], smax[3]));

    float s = 0.f;
#pragma unroll
    for (int j = 0; j < 8; ++j) {
        int t = j * 256 + tid;
        vals[j] = (t < T) ? __expf(vals[j] - m) : 0.f;
        s += vals[j];
    }
#pragma unroll
    for (int off = 32; off >= 1; off >>= 1) s += __shfl_xor(s, off);
    if (lane == 0) ssum[wid] = s;
    __syncthreads();
    s = ssum[0] + ssum[1] + ssum[2] + ssum[3];
    float inv = 1.f / s;
#pragma unroll
    for (int j = 0; j < 8; ++j) {
        int t = j * 256 + tid;
        if (t < T) weights[(size_t)b * T + t] = vals[j] * inv;
    }
}

// K4: partial context. grid(NCHUNK, B), block(128). Each thread one d-quad.
__global__ __launch_bounds__(128) void ctx_partial_kernel(const float* __restrict__ memory,
                                   const float* __restrict__ weights,
                                   float* __restrict__ partial) {
    int b = blockIdx.y, s = blockIdx.x;
    int dq = threadIdx.x;                       // 0..127
    int tbeg = s * TCHUNK;
    __shared__ float sw[TCHUNK];
    const float* w = weights + (size_t)b * T;
    for (int j = threadIdx.x; j < TCHUNK; j += 128) sw[j] = w[tbeg + j];
    __syncthreads();
    const float4* mem4 = (const float4*)(memory + (size_t)b * T * D_MEM);
    float4 acc = {0.f, 0.f, 0.f, 0.f};
#pragma unroll 10
    for (int j = 0; j < TCHUNK; ++j) {
        float wt = sw[j];
        float4 mv = mem4[(size_t)(tbeg + j) * (D_MEM / 4) + dq];
        acc.x = fmaf(wt, mv.x, acc.x);
        acc.y = fmaf(wt, mv.y, acc.y);
        acc.z = fmaf(wt, mv.z, acc.z);
        acc.w = fmaf(wt, mv.w, acc.w);
    }
    ((float4*)(partial + ((size_t)s * B + b) * D_MEM))[dq] = acc;
}

// K5: reduce NCHUNK partials -> context in d_out. grid(B*D_MEM/256), block(256)
__global__ __launch_bounds__(256) void ctx_reduce_kernel(const float* __restrict__ partial,
                                  float* __restrict__ ctx) {
    int idx = blockIdx.x * 256 + threadIdx.x;   // 0 .. B*D_MEM-1
    float acc = 0.f;
#pragma unroll
    for (int s = 0; s < NCHUNK; ++s)
        acc += partial[(size_t)s * B * D_MEM + idx];
    ctx[idx] = acc;
}

extern "C" void kernel_launch(void* const* d_in, const int* in_sizes, int n_in,
                              void* d_out, int out_size, void* d_ws, size_t ws_size,
                              hipStream_t stream) {
    const float* hidden = (const float*)d_in[0];   // [B,1,D_Q]
    const float* memory = (const float*)d_in[1];   // [B,T,D_MEM]
    const float* pmem   = (const float*)d_in[2];   // [B,T,D_ATT]
    const float* aw     = (const float*)d_in[3];   // [B,2,T]
    const float* Wq     = (const float*)d_in[4];   // [D_Q,D_ATT]
    const float* Wconv  = (const float*)d_in[5];   // [C_LOC,2,K]
    const float* bconv  = (const float*)d_in[6];   // [C_LOC]
    const float* Wloc   = (const float*)d_in[7];   // [C_LOC,D_ATT]
    const float* v      = (const float*)d_in[8];   // [D_ATT]

    float* out_ctx = (float*)d_out;                // [B,D_MEM]
    float* out_w   = (float*)d_out + B * D_MEM;    // [B,T]

    float* ws       = (float*)d_ws;
    float* pq       = ws + WS_PQ;
    float* energies = ws + WS_ENERGY;
    float* partial  = ws + WS_PARTIAL;

    pq_kernel<<<B, 512, 0, stream>>>(hidden, Wq, pq);
    energy_kernel<<<dim3(T / CH, B), 256, 0, stream>>>(aw, pmem, pq, Wconv, bconv,
                                                       Wloc, v, energies);
    softmax_kernel<<<B, 256, 0, stream>>>(energies, out_w);
    ctx_partial_kernel<<<dim3(NCHUNK, B), 128, 0, stream>>>(memory, out_w, partial);
    ctx_reduce_kernel<<<(B * D_MEM) / 256, 256, 0, stream>>>(partial, out_ctx);
}

// Round 3
// 508.176 us; speedup vs baseline: 1.0718x; 1.0292x over previous
//
#include <hip/hip_runtime.h>
#include <hip/hip_bf16.h>

#define B 64
#define T 2000
#define D_MEM 512
#define D_Q 1024
#define D_ATT 128
#define C_LOC 32
#define K 31

// mega-kernel tiling: 20 chunks of 100 t's per batch -> grid(20,64)
#define CH2 100
#define NCH2 (T / CH2)          // 20
#define TPG 13                  // t's per thread-group: t_local = g + 8*j, j<13
#define NPART (NCH2 * 2)        // 40 context partials (2 half-chunks per block)

// ws layout (floats)
#define WS_PQ    0
#define WS_EXPW  (WS_PQ + B * D_ATT)     // unnormalized exp(e)  [B,T]
#define WS_SUMS  (WS_EXPW + B * T)       // per-chunk sums       [B,NCH2]
#define WS_PART  (WS_SUMS + B * NCH2)    // ctx partials         [NPART,B,D_MEM]

__device__ __forceinline__ float tanh_fast(float x) {
    float e = __expf(2.f * x);
    return 1.f - 2.f / (e + 1.f);
}

// K1: pq[b,d] = sum_i h[b,i]*Wq[i,d]. grid(B), block(512): 4 i-slices x 128 d.
__global__ __launch_bounds__(512) void pq_kernel(const float* __restrict__ h,
                                                 const float* __restrict__ Wq,
                                                 float* __restrict__ pq) {
    int b = blockIdx.x;
    int tid = threadIdx.x;
    int ty = tid >> 7;          // 0..3  (i-slice)
    int d  = tid & 127;         // 0..127
    __shared__ float sh[D_Q];
    __shared__ float red[4][D_ATT];
    const float* hb = h + (size_t)b * D_Q;
    if (tid < D_Q / 4) ((float4*)sh)[tid] = ((const float4*)hb)[tid];
    __syncthreads();
    float acc = 0.f;
    int ibeg = ty * 256;
#pragma unroll 8
    for (int i2 = 0; i2 < 256; ++i2) {
        int i = ibeg + i2;
        acc = fmaf(sh[i], Wq[(size_t)i * D_ATT + d], acc);
    }
    red[ty][d] = acc;
    __syncthreads();
    if (ty == 0)
        pq[b * D_ATT + d] = red[0][d] + red[1][d] + red[2][d] + red[3][d];
}

// K2: per (chunk s, batch b): conv -> loc-proj -> energy -> exp (NO max
// subtraction: |e| <= ||v||_1 ~ 10, exp fits fp32 easily) -> chunk sum ->
// unnormalized context partial over the chunk's 100 rows of `memory`.
__global__ __launch_bounds__(256) void mega_kernel(
    const float* __restrict__ aw, const float* __restrict__ pmem,
    const float* __restrict__ pq, const float* __restrict__ Wconv,
    const float* __restrict__ bconv, const float* __restrict__ Wloc,
    const float* __restrict__ v, const float* __restrict__ memory,
    float* __restrict__ expw, float* __restrict__ sums,
    float* __restrict__ partial) {
    const int s = blockIdx.x, b = blockIdx.y;
    const int t0 = s * CH2;
    const int tid = threadIdx.x;

    __shared__ float s_aw[2][CH2 + K - 1];   // [2][130]
    __shared__ float s_wc[2 * K * C_LOC];    // transposed conv weights
    __shared__ float s_loc[CH2 + 4][C_LOC];  // rows 100..103 = scratch
    __shared__ float s_pq[D_ATT];
    __shared__ float s_e[CH2];               // exp(e) for this chunk
    __shared__ float s_red[2];

    const int AWW = CH2 + K - 1;             // 130
    for (int j = tid; j < 2 * AWW; j += 256) {
        int i = j / AWW, o = j - i * AWW;
        int t = t0 - (K / 2) + o;
        s_aw[i][o] = (t >= 0 && t < T) ? aw[((size_t)b * 2 + i) * T + t] : 0.f;
    }
    for (int j = tid; j < C_LOC * 2 * K; j += 256) {
        int c = j / (2 * K), r = j - c * 2 * K;
        int i = r / K, k = r - i * K;
        s_wc[(i * K + k) * C_LOC + c] = Wconv[j];
    }
    if (tid < D_ATT) s_pq[tid] = pq[b * D_ATT + tid];
    __syncthreads();

    // ---- conv: thread (g=tid>>5, c=tid&31), t_local = g + 8j, j<13 ----
    {
        int g = tid >> 5, c = tid & 31;
        float bc = bconv[c];
        float acc[TPG];
#pragma unroll
        for (int j = 0; j < TPG; ++j) acc[j] = bc;
#pragma unroll
        for (int i = 0; i < 2; ++i) {
#pragma unroll
            for (int k = 0; k < K; ++k) {
                float wv = s_wc[(i * K + k) * C_LOC + c];
#pragma unroll
                for (int j = 0; j < TPG; ++j)
                    acc[j] = fmaf(s_aw[i][g + 8 * j + k], wv, acc[j]);
            }
        }
#pragma unroll
        for (int j = 0; j < TPG; ++j) s_loc[g + 8 * j][c] = acc[j];
    }
    __syncthreads();

    // ---- energy + exp: thread (g, dd=tid&31) owns d-quad dd ----
    {
        int g = tid >> 5, dd = tid & 31;
        float4 pqv = ((const float4*)s_pq)[dd];
        float4 vv  = ((const float4*)v)[dd];
        float4 pl[TPG];
#pragma unroll
        for (int j = 0; j < TPG; ++j) pl[j] = make_float4(0.f, 0.f, 0.f, 0.f);
#pragma unroll
        for (int c = 0; c < C_LOC; ++c) {
            float4 w = ((const float4*)(Wloc + c * D_ATT))[dd];
#pragma unroll
            for (int j = 0; j < TPG; ++j) {
                float l = s_loc[g + 8 * j][c];   // rows>=100 read scratch, unused
                pl[j].x = fmaf(l, w.x, pl[j].x);
                pl[j].y = fmaf(l, w.y, pl[j].y);
                pl[j].z = fmaf(l, w.z, pl[j].z);
                pl[j].w = fmaf(l, w.w, pl[j].w);
            }
        }
#pragma unroll
        for (int j = 0; j < TPG; ++j) {
            int tl = g + 8 * j;
            if (tl < CH2) {              // whole waves branch together here
                int t = t0 + tl;
                float4 pm = ((const float4*)(pmem + ((size_t)b * T + t) * D_ATT))[dd];
                float e = vv.x * tanh_fast(pqv.x + pl[j].x + pm.x)
                        + vv.y * tanh_fast(pqv.y + pl[j].y + pm.y)
                        + vv.z * tanh_fast(pqv.z + pl[j].z + pm.z)
                        + vv.w * tanh_fast(pqv.w + pl[j].w + pm.w);
#pragma unroll
                for (int off = 16; off >= 1; off >>= 1)
                    e += __shfl_xor(e, off);
                if (dd == 0) s_e[tl] = __expf(e);
            }
        }
    }
    __syncthreads();

    // ---- chunk sum + stash unnormalized weights ----
    if (tid < 128) {
        float vsum = (tid < CH2) ? s_e[tid] : 0.f;
        if (tid < CH2) expw[(size_t)b * T + t0 + tid] = vsum;
        float r = vsum;
#pragma unroll
        for (int off = 32; off >= 1; off >>= 1) r += __shfl_xor(r, off);
        if ((tid & 63) == 0) s_red[tid >> 6] = r;
    }
    __syncthreads();
    if (tid == 0) sums[b * NCH2 + s] = s_red[0] + s_red[1];

    // ---- unnormalized context partial over this chunk ----
    {
        int dq = tid & 127, h = tid >> 7;    // h: half-chunk (50 t's)
        const float4* mem4 =
            (const float4*)(memory + ((size_t)b * T + t0 + h * 50) * D_MEM);
        float4 acc = {0.f, 0.f, 0.f, 0.f};
#pragma unroll 10
        for (int j = 0; j < 50; ++j) {
            float wt = s_e[h * 50 + j];
            float4 mv = mem4[(size_t)j * (D_MEM / 4) + dq];
            acc.x = fmaf(wt, mv.x, acc.x);
            acc.y = fmaf(wt, mv.y, acc.y);
            acc.z = fmaf(wt, mv.z, acc.z);
            acc.w = fmaf(wt, mv.w, acc.w);
        }
        ((float4*)(partial + ((size_t)(s * 2 + h) * B + b) * D_MEM))[dq] = acc;
    }
}

// K3: finalize. grid(B), block(256).
// sum_b = sum of 20 chunk sums; out_w = expw/sum_b; out_ctx = (sum partials)/sum_b.
__global__ __launch_bounds__(256) void finalize_kernel(
    const float* __restrict__ expw, const float* __restrict__ sums,
    const float* __restrict__ partial, float* __restrict__ out_w,
    float* __restrict__ out_ctx) {
    int b = blockIdx.x, tid = threadIdx.x;
    __shared__ float s_inv;
    if (tid < 64) {
        float r = (tid < NCH2) ? sums[b * NCH2 + tid] : 0.f;
#pragma unroll
        for (int off = 32; off >= 1; off >>= 1) r += __shfl_xor(r, off);
        if (tid == 0) s_inv = 1.f / r;
    }
    __syncthreads();
    float inv = s_inv;
    for (int t = tid; t < T; t += 256)
        out_w[(size_t)b * T + t] = expw[(size_t)b * T + t] * inv;
    if (tid < 128) {
        const float4* p4 = (const float4*)partial;
        float4 acc = {0.f, 0.f, 0.f, 0.f};
#pragma unroll
        for (int p = 0; p < NPART; ++p) {
            float4 pv = p4[((size_t)p * B + b) * (D_MEM / 4) + tid];
            acc.x += pv.x; acc.y += pv.y; acc.z += pv.z; acc.w += pv.w;
        }
        acc.x *= inv; acc.y *= inv; acc.z *= inv; acc.w *= inv;
        ((float4*)(out_ctx + (size_t)b * D_MEM))[tid] = acc;
    }
}

extern "C" void kernel_launch(void* const* d_in, const int* in_sizes, int n_in,
                              void* d_out, int out_size, void* d_ws, size_t ws_size,
                              hipStream_t stream) {
    const float* hidden = (const float*)d_in[0];   // [B,1,D_Q]
    const float* memory = (const float*)d_in[1];   // [B,T,D_MEM]
    const float* pmem   = (const float*)d_in[2];   // [B,T,D_ATT]
    const float* aw     = (const float*)d_in[3];   // [B,2,T]
    const float* Wq     = (const float*)d_in[4];   // [D_Q,D_ATT]
    const float* Wconv  = (const float*)d_in[5];   // [C_LOC,2,K]
    const float* bconv  = (const float*)d_in[6];   // [C_LOC]
    const float* Wloc   = (const float*)d_in[7];   // [C_LOC,D_ATT]
    const float* v      = (const float*)d_in[8];   // [D_ATT]

    float* out_ctx = (float*)d_out;                // [B,D_MEM]
    float* out_w   = (float*)d_out + B * D_MEM;    // [B,T]

    float* ws      = (float*)d_ws;
    float* pqp     = ws + WS_PQ;
    float* expw    = ws + WS_EXPW;
    float* sums    = ws + WS_SUMS;
    float* partial = ws + WS_PART;

    pq_kernel<<<B, 512, 0, stream>>>(hidden, Wq, pqp);
    mega_kernel<<<dim3(NCH2, B), 256, 0, stream>>>(aw, pmem, pqp, Wconv, bconv,
                                                   Wloc, v, memory, expw, sums,
                                                   partial);
    finalize_kernel<<<B, 256, 0, stream>>>(expw, sums, partial, out_w, out_ctx);
}

// Round 4
// 462.614 us; speedup vs baseline: 1.1774x; 1.0985x over previous
//
#include <hip/hip_runtime.h>
#include <hip/hip_bf16.h>

#define B 64
#define T 2000
#define D_MEM 512
#define D_Q 1024
#define D_ATT 128
#define C_LOC 32
#define K 31

// mega-kernel tiling: 20 chunks of 100 t's per batch -> grid(20,64)
#define CH2 100
#define NCH2 (T / CH2)          // 20
#define TPG 13                  // conv: t_local = g + 8*j, j<13
#define NPART (NCH2 * 2)        // 40 context partials (2 half-chunks per block)

// ws layout (floats)
#define WS_PQ    0
#define WS_EXPW  (WS_PQ + B * D_ATT)     // unnormalized exp(e)  [B,T]
#define WS_SUMS  (WS_EXPW + B * T)       // per-chunk sums       [B,NCH2]
#define WS_PART  (WS_SUMS + B * NCH2)    // ctx partials         [NPART,B,D_MEM]

__device__ __forceinline__ float tanh_fast(float x) {
    float e = __expf(2.f * x);
    return 1.f - 2.f / (e + 1.f);
}

// K1: pq[b,d] = sum_i h[b,i]*Wq[i,d]. grid(B), block(512): 4 i-slices x 128 d.
__global__ __launch_bounds__(512) void pq_kernel(const float* __restrict__ h,
                                                 const float* __restrict__ Wq,
                                                 float* __restrict__ pq) {
    int b = blockIdx.x;
    int tid = threadIdx.x;
    int ty = tid >> 7;          // 0..3  (i-slice)
    int d  = tid & 127;         // 0..127
    __shared__ float sh[D_Q];
    __shared__ float red[4][D_ATT];
    const float* hb = h + (size_t)b * D_Q;
    if (tid < D_Q / 4) ((float4*)sh)[tid] = ((const float4*)hb)[tid];
    __syncthreads();
    float acc = 0.f;
    int ibeg = ty * 256;
#pragma unroll 8
    for (int i2 = 0; i2 < 256; ++i2) {
        int i = ibeg + i2;
        acc = fmaf(sh[i], Wq[(size_t)i * D_ATT + d], acc);
    }
    red[ty][d] = acc;
    __syncthreads();
    if (ty == 0)
        pq[b * D_ATT + d] = red[0][d] + red[1][d] + red[2][d] + red[3][d];
}

// K2: per (chunk s, batch b): conv -> loc-proj -> energy -> exp (no max
// subtraction: |e| <= ||v||_1 ~ 10, exp fits fp32) -> chunk sum ->
// unnormalized context partial over the chunk's 100 rows of `memory`.
// Register discipline: energy accumulators processed in 4 chunks of 4 t's
// (pl[4] live = 16 VGPR, not pl[13]=52 which spilled at VGPR=256 in R3).
__global__ __launch_bounds__(256, 4) void mega_kernel(
    const float* __restrict__ aw, const float* __restrict__ pmem,
    const float* __restrict__ pq, const float* __restrict__ Wconv,
    const float* __restrict__ bconv, const float* __restrict__ Wloc,
    const float* __restrict__ v, const float* __restrict__ memory,
    float* __restrict__ expw, float* __restrict__ sums,
    float* __restrict__ partial) {
    const int s = blockIdx.x, b = blockIdx.y;
    const int t0 = s * CH2;
    const int tid = threadIdx.x;

    __shared__ float s_aw[2][CH2 + K - 1];   // [2][130]
    __shared__ float s_wc[2 * K * C_LOC];    // transposed conv weights
    __shared__ float s_loc[128][C_LOC];      // rows 104..127 never written (reads masked)
    __shared__ float s_wloc[C_LOC * D_ATT];  // Wloc staged: 16 KB
    __shared__ float s_pq[D_ATT];
    __shared__ float s_e[CH2];               // exp(e) for this chunk
    __shared__ float s_red[2];

    const int AWW = CH2 + K - 1;             // 130
    for (int j = tid; j < 2 * AWW; j += 256) {
        int i = j / AWW, o = j - i * AWW;
        int t = t0 - (K / 2) + o;
        s_aw[i][o] = (t >= 0 && t < T) ? aw[((size_t)b * 2 + i) * T + t] : 0.f;
    }
    for (int j = tid; j < C_LOC * 2 * K; j += 256) {
        int c = j / (2 * K), r = j - c * 2 * K;
        int i = r / K, k = r - i * K;
        s_wc[(i * K + k) * C_LOC + c] = Wconv[j];
    }
    // stage Wloc (16 KB, coalesced float4)
    for (int j = tid; j < C_LOC * D_ATT / 4; j += 256)
        ((float4*)s_wloc)[j] = ((const float4*)Wloc)[j];
    if (tid < D_ATT) s_pq[tid] = pq[b * D_ATT + tid];
    __syncthreads();

    // ---- conv: thread (g=tid>>5, c=tid&31), t_local = g + 8j, j<13 ----
    {
        int g = tid >> 5, c = tid & 31;
        float bc = bconv[c];
        float acc[TPG];
#pragma unroll
        for (int j = 0; j < TPG; ++j) acc[j] = bc;
#pragma unroll
        for (int i = 0; i < 2; ++i) {
#pragma unroll
            for (int k = 0; k < K; ++k) {
                float wv = s_wc[(i * K + k) * C_LOC + c];
#pragma unroll
                for (int j = 0; j < TPG; ++j)
                    acc[j] = fmaf(s_aw[i][g + 8 * j + k], wv, acc[j]);
            }
        }
#pragma unroll
        for (int j = 0; j < TPG; ++j) s_loc[g + 8 * j][c] = acc[j];
    }
    __syncthreads();

    // ---- energy + exp, in 4 chunks of 4 t's per thread-group ----
    {
        int g = tid >> 5, dd = tid & 31;
        float4 pqv = ((const float4*)s_pq)[dd];
        float4 vv  = ((const float4*)v)[dd];
#pragma unroll
        for (int jc = 0; jc < 4; ++jc) {
            float4 pl[4];
#pragma unroll
            for (int jj = 0; jj < 4; ++jj) pl[jj] = make_float4(0.f, 0.f, 0.f, 0.f);
#pragma unroll
            for (int c = 0; c < C_LOC; ++c) {
                float4 w = ((const float4*)s_wloc)[c * (D_ATT / 4) + dd];
#pragma unroll
                for (int jj = 0; jj < 4; ++jj) {
                    // rows >=104 unwritten garbage; results masked below
                    float l = s_loc[g + 8 * (jc * 4 + jj)][c];
                    pl[jj].x = fmaf(l, w.x, pl[jj].x);
                    pl[jj].y = fmaf(l, w.y, pl[jj].y);
                    pl[jj].z = fmaf(l, w.z, pl[jj].z);
                    pl[jj].w = fmaf(l, w.w, pl[jj].w);
                }
            }
#pragma unroll
            for (int jj = 0; jj < 4; ++jj) {
                int tl = g + 8 * (jc * 4 + jj);
                if (tl < CH2) {          // uniform across the 32 dd-lanes
                    int t = t0 + tl;
                    float4 pm = ((const float4*)(pmem + ((size_t)b * T + t) * D_ATT))[dd];
                    float e = vv.x * tanh_fast(pqv.x + pl[jj].x + pm.x)
                            + vv.y * tanh_fast(pqv.y + pl[jj].y + pm.y)
                            + vv.z * tanh_fast(pqv.z + pl[jj].z + pm.z)
                            + vv.w * tanh_fast(pqv.w + pl[jj].w + pm.w);
#pragma unroll
                    for (int off = 16; off >= 1; off >>= 1)
                        e += __shfl_xor(e, off);
                    if (dd == 0) s_e[tl] = __expf(e);
                }
            }
        }
    }
    __syncthreads();

    // ---- chunk sum + stash unnormalized weights ----
    if (tid < 128) {
        float vsum = (tid < CH2) ? s_e[tid] : 0.f;
        if (tid < CH2) expw[(size_t)b * T + t0 + tid] = vsum;
        float r = vsum;
#pragma unroll
        for (int off = 32; off >= 1; off >>= 1) r += __shfl_xor(r, off);
        if ((tid & 63) == 0) s_red[tid >> 6] = r;
    }
    __syncthreads();
    if (tid == 0) sums[b * NCH2 + s] = s_red[0] + s_red[1];

    // ---- unnormalized context partial over this chunk ----
    {
        int dq = tid & 127, h = tid >> 7;    // h: half-chunk (50 t's)
        const float4* mem4 =
            (const float4*)(memory + ((size_t)b * T + t0 + h * 50) * D_MEM);
        float4 acc = {0.f, 0.f, 0.f, 0.f};
#pragma unroll 10
        for (int j = 0; j < 50; ++j) {
            float wt = s_e[h * 50 + j];
            float4 mv = mem4[(size_t)j * (D_MEM / 4) + dq];
            acc.x = fmaf(wt, mv.x, acc.x);
            acc.y = fmaf(wt, mv.y, acc.y);
            acc.z = fmaf(wt, mv.z, acc.z);
            acc.w = fmaf(wt, mv.w, acc.w);
        }
        ((float4*)(partial + ((size_t)(s * 2 + h) * B + b) * D_MEM))[dq] = acc;
    }
}

// K3: finalize. grid(B), block(256).
__global__ __launch_bounds__(256) void finalize_kernel(
    const float* __restrict__ expw, const float* __restrict__ sums,
    const float* __restrict__ partial, float* __restrict__ out_w,
    float* __restrict__ out_ctx) {
    int b = blockIdx.x, tid = threadIdx.x;
    __shared__ float s_inv;
    if (tid < 64) {
        float r = (tid < NCH2) ? sums[b * NCH2 + tid] : 0.f;
#pragma unroll
        for (int off = 32; off >= 1; off >>= 1) r += __shfl_xor(r, off);
        if (tid == 0) s_inv = 1.f / r;
    }
    __syncthreads();
    float inv = s_inv;
    for (int t = tid; t < T; t += 256)
        out_w[(size_t)b * T + t] = expw[(size_t)b * T + t] * inv;
    if (tid < 128) {
        const float4* p4 = (const float4*)partial;
        float4 acc = {0.f, 0.f, 0.f, 0.f};
#pragma unroll
        for (int p = 0; p < NPART; ++p) {
            float4 pv = p4[((size_t)p * B + b) * (D_MEM / 4) + tid];
            acc.x += pv.x; acc.y += pv.y; acc.z += pv.z; acc.w += pv.w;
        }
        acc.x *= inv; acc.y *= inv; acc.z *= inv; acc.w *= inv;
        ((float4*)(out_ctx + (size_t)b * D_MEM))[tid] = acc;
    }
}

extern "C" void kernel_launch(void* const* d_in, const int* in_sizes, int n_in,
                              void* d_out, int out_size, void* d_ws, size_t ws_size,
                              hipStream_t stream) {
    const float* hidden = (const float*)d_in[0];   // [B,1,D_Q]
    const float* memory = (const float*)d_in[1];   // [B,T,D_MEM]
    const float* pmem   = (const float*)d_in[2];   // [B,T,D_ATT]
    const float* aw     = (const float*)d_in[3];   // [B,2,T]
    const float* Wq     = (const float*)d_in[4];   // [D_Q,D_ATT]
    const float* Wconv  = (const float*)d_in[5];   // [C_LOC,2,K]
    const float* bconv  = (const float*)d_in[6];   // [C_LOC]
    const float* Wloc   = (const float*)d_in[7];   // [C_LOC,D_ATT]
    const float* v      = (const float*)d_in[8];   // [D_ATT]

    float* out_ctx = (float*)d_out;                // [B,D_MEM]
    float* out_w   = (float*)d_out + B * D_MEM;    // [B,T]

    float* ws      = (float*)d_ws;
    float* pqp     = ws + WS_PQ;
    float* expw    = ws + WS_EXPW;
    float* sums    = ws + WS_SUMS;
    float* partial = ws + WS_PART;

    pq_kernel<<<B, 512, 0, stream>>>(hidden, Wq, pqp);
    mega_kernel<<<dim3(NCH2, B), 256, 0, stream>>>(aw, pmem, pqp, Wconv, bconv,
                                                   Wloc, v, memory, expw, sums,
                                                   partial);
    finalize_kernel<<<B, 256, 0, stream>>>(expw, sums, partial, out_w, out_ctx);
}